// Round 4
// baseline (279.723 us; speedup 1.0000x reference)
//
#include <hip/hip_runtime.h>

#define BB 4
#define NN 1024
#define KK 9
#define C  32
#define CM 128
#define M  (BB*NN)       // 4096 rows
#define EPSB 1e-5f
#define SLOPE 0.01f

#define GRID_BLOCKS 512
#define SCH 4            // n-chunks (part slots)
#define NCH 256          // n per chunk
#define KPAD 296         // padded row stride (f16) for comp_w tiles
#define CHUNK_F16 (32*KPAD)   // 9472 f16 per (b,nc,sub) tile

typedef _Float16 f16x8 __attribute__((ext_vector_type(8)));
typedef _Float16 f16x4 __attribute__((ext_vector_type(4)));
typedef float    f32x4 __attribute__((ext_vector_type(4)));

__device__ __forceinline__ float leaky(float x){ return x > 0.f ? x : SLOPE*x; }

// Device-scope grid barrier: one fresh counter per use (no reset logic).
// Counters are zeroed by hipMemsetAsync before launch. Release-RMW flushes
// this XCD's L2; acquire-load invalidates consumer L2 (cross-XCD visibility).
__device__ __forceinline__ void gridbar(int* cnt){
  __syncthreads();
  if (threadIdx.x == 0){
    __threadfence();
    __hip_atomic_fetch_add(cnt, 1, __ATOMIC_ACQ_REL, __HIP_MEMORY_SCOPE_AGENT);
    while (__hip_atomic_load(cnt, __ATOMIC_ACQUIRE, __HIP_MEMORY_SCOPE_AGENT) < GRID_BLOCKS){
      __builtin_amdgcn_s_sleep(2);
    }
  }
  __syncthreads();
}

// ---------------------------------------------------------------------------
// One fused kernel, plain launch, 512 blocks x 256 threads, 5 phases
// separated by manual grid barriers. Phase bodies identical to the
// r2-verified standalone kernels. 40KB LDS union, __launch_bounds__(256,2)
// guarantees >=2 blocks/CU -> all 512 blocks co-resident (no deadlock).
// ---------------------------------------------------------------------------
__global__ __launch_bounds__(256, 2) void fused_all(
    const float* __restrict__ pos,
    const float* __restrict__ weights,
    const float* __restrict__ kpos,
    const float* __restrict__ conv_w,
    const float* __restrict__ bn_g,  const float* __restrict__ bn_b,
    const float* __restrict__ w1,    const float* __restrict__ b1,
    const float* __restrict__ bn1_g, const float* __restrict__ bn1_b,
    const float* __restrict__ w2,    const float* __restrict__ b2,
    float* __restrict__ out,
    _Float16* __restrict__ cwh,
    float* __restrict__ part,
    float* __restrict__ z,
    float* __restrict__ y,
    float* __restrict__ h,
    float* __restrict__ stats,
    int* __restrict__ bar)
{
  __shared__ __align__(16) char smem[40960];
  int bid = blockIdx.x;
  int tid = threadIdx.x;

  // ======== Phase A: comp_w f16 producer (+ zero stats) — 384 blocks ========
  if (bid == 0){ for (int i = tid; i < 320; i += 256) stats[i] = 0.f; }
  if (bid < 384){
    float* cwl = (float*)smem;     // 12 KB conv_w k-slice
    int kt  = bid % 3;
    int sub = (bid/3)&7, nc = (bid/24)&3, b = bid/96;

    const float4* cs = (const float4*)(conv_w + kt*3*C*C);
    float4* cd = (float4*)cwl;
    for (int v = tid; v < 768; v += 256) cd[v] = cs[v];

    int nl = tid & 31, dq = tid >> 5;
    int row = ((b*4 + nc)*8 + sub)*32 + nl;
    float wreg[32];
    const float4* wr = (const float4*)(weights + (size_t)row*C);
    #pragma unroll
    for (int j = 0; j < 8; ++j){
      float4 t = wr[j];
      wreg[4*j]=t.x; wreg[4*j+1]=t.y; wreg[4*j+2]=t.z; wreg[4*j+3]=t.w;
    }
    __syncthreads();

    _Float16* outb = cwh + (size_t)((b*4+nc)*8 + sub)*CHUNK_F16;
    const float4* cv = (const float4*)cwl;
    #pragma unroll
    for (int kl = 0; kl < 3; ++kl){
      float a0=0.f, a1=0.f, a2=0.f, a3=0.f;
      #pragma unroll
      for (int c = 0; c < C; ++c){
        float4 t = cv[kl*256 + c*8 + dq];
        a0 += wreg[c]*t.x; a1 += wreg[c]*t.y; a2 += wreg[c]*t.z; a3 += wreg[c]*t.w;
      }
      int k = kt*3 + kl;
      outb[(dq*4+0)*KPAD + k*32 + nl] = (_Float16)a0;
      outb[(dq*4+1)*KPAD + k*32 + nl] = (_Float16)a1;
      outb[(dq*4+2)*KPAD + k*32 + nl] = (_Float16)a2;
      outb[(dq*4+3)*KPAD + k*32 + nl] = (_Float16)a3;
    }
  }
  gridbar(&bar[0]);

  // ======== Phase B: flash-style MFMA Gaussian mixture — all 512 blocks ====
  {
    _Float16* km = (_Float16*)smem;            // [i][K] 18944 B
    _Float16* cw = (_Float16*)(smem + 18944);  // [c][K] 18944 B
    float* pnl   = (float*)(smem + 37888);     // 2 KB
    int nc = bid & 3, it = (bid>>2)&31, b = bid>>7;
    int lane = tid & 63, wid = tid >> 6;
    int i0 = (wid>>1)*16, c0 = (wid&1)*16;
    int mm = lane & 15, quad = lane >> 4;

    const float* pbase = pos + (size_t)(b*NN + nc*NCH)*2;
    for (int v = tid; v < NCH*2; v += 256) pnl[v] = pbase[v];

    int ig = tid >> 3, np = tid & 7;
    float pix = pos[(size_t)(b*NN + it*32 + ig)*2];
    float piy = pos[(size_t)(b*NN + it*32 + ig)*2 + 1];
    float kx[KK], ky[KK];
    #pragma unroll
    for (int k = 0; k < KK; ++k){ kx[k] = kpos[2*k]; ky[k] = kpos[2*k+1]; }

    f32x4 acc = {0.f,0.f,0.f,0.f};
    __syncthreads();

    for (int s = 0; s < 8; ++s){
      const float4* srcs = (const float4*)(cwh + (size_t)((b*4+nc)*8 + s)*CHUNK_F16);
      float4* dst = (float4*)cw;
      for (int v = tid; v < CHUNK_F16/8; v += 256) dst[v] = srcs[v];

      float dx[4], dy[4];
      #pragma unroll
      for (int jj = 0; jj < 4; ++jj){
        int nl = np*4 + jj;
        dx[jj] = pix - pnl[2*(s*32+nl)];
        dy[jj] = piy - pnl[2*(s*32+nl)+1];
      }
      #pragma unroll
      for (int k = 0; k < KK; ++k){
        f16x4 ev;
        #pragma unroll
        for (int jj = 0; jj < 4; ++jj){
          float ddx = dx[jj]-kx[k], ddy = dy[jj]-ky[k];
          ev[jj] = (_Float16)__expf(-0.5f*(ddx*ddx + ddy*ddy));
        }
        *(f16x4*)&km[ig*KPAD + k*32 + np*4] = ev;
      }
      __syncthreads();

      #pragma unroll
      for (int ks = 0; ks < 9; ++ks){
        f16x8 a  = *(const f16x8*)&km[(i0+mm)*KPAD + ks*32 + quad*8];
        f16x8 bf = *(const f16x8*)&cw[(c0+mm)*KPAD + ks*32 + quad*8];
        acc = __builtin_amdgcn_mfma_f32_16x16x32_f16(a, bf, acc, 0, 0, 0);
      }
      __syncthreads();
    }

    int grow0 = b*NN + it*32 + i0;
    #pragma unroll
    for (int r = 0; r < 4; ++r){
      int grow = grow0 + quad*4 + r;
      part[((size_t)nc*M + grow)*C + c0 + mm] = acc[r];
    }
  }
  gridbar(&bar[1]);

  // ======== Phase C: z = leaky(sum part) + channel stats — all blocks ======
  {
    float* ls1 = (float*)smem;
    float* ls2 = ls1 + C;
    if (tid < C){ ls1[tid]=0.f; ls2[tid]=0.f; }
    __syncthreads();
    size_t idx = (size_t)bid*256 + tid;
    float s = 0.f;
    #pragma unroll
    for (int p = 0; p < SCH; ++p) s += part[(size_t)p*M*C + idx];
    s = leaky(s);
    z[idx] = s;
    atomicAdd(&ls1[tid & (C-1)], s);
    atomicAdd(&ls2[tid & (C-1)], s*s);
    __syncthreads();
    if (tid < C){ atomicAdd(&stats[tid], ls1[tid]); atomicAdd(&stats[C+tid], ls2[tid]); }
  }
  gridbar(&bar[2]);

  // ======== Phase D: BN + residual + MLP layer 1 + stats — 256 blocks ======
  if (bid < 256){
    float* w1l = (float*)smem;              // 16 KB
    float* yl  = (float*)(smem + 16384);    // 2 KB
    float* lt1 = (float*)(smem + 18432);    // 512 B
    float* lt2 = (float*)(smem + 18944);    // 512 B
    int row0 = bid * 16;
    for (int i = tid; i < C*CM; i += 256) w1l[i] = w1[i];
    if (tid < CM){ lt1[tid]=0.f; lt2[tid]=0.f; }
    #pragma unroll
    for (int j = 0; j < 2; ++j){
      int e = tid + j*256;
      int c  = e & (C-1);
      int rl = e >> 5;
      float s1 = stats[c], s2 = stats[C + c];
      float mean = s1 * (1.f/M);
      float var  = s2 * (1.f/M) - mean*mean;
      float sc = bn_g[c] * rsqrtf(var + EPSB);
      float sh = bn_b[c] - mean*sc;
      int row = row0 + rl;
      float v = z[(size_t)row*C + c]*sc + sh + weights[(size_t)row*C + c];
      yl[e] = v;
      y[(size_t)row*C + c] = v;
    }
    __syncthreads();
    #pragma unroll
    for (int j = 0; j < 8; ++j){
      int e = tid + j*256;
      int col = e & (CM-1);
      int rl  = e >> 7;
      float acc = b1[col];
      #pragma unroll
      for (int c = 0; c < C; ++c) acc += yl[rl*C + c] * w1l[c*CM + col];
      acc = leaky(acc);
      h[(size_t)(row0+rl)*CM + col] = acc;
      atomicAdd(&lt1[col], acc);
      atomicAdd(&lt2[col], acc*acc);
    }
    __syncthreads();
    if (tid < CM){
      atomicAdd(&stats[2*C + tid],      lt1[tid]);
      atomicAdd(&stats[2*C + CM + tid], lt2[tid]);
    }
  }
  gridbar(&bar[3]);

  // ======== Phase E: BN1 + MLP layer 2 + final residual — 256 blocks =======
  if (bid < 256){
    float* w2l = (float*)smem;              // 16 KB
    float* hl  = (float*)(smem + 16384);    // 8 KB
    int row0 = bid * 16;
    for (int i = tid; i < CM*C; i += 256) w2l[i] = w2[i];
    #pragma unroll
    for (int j = 0; j < 8; ++j){
      int e = tid + j*256;
      int col = e & (CM-1);
      int rl  = e >> 7;
      float t1 = stats[2*C + col], t2 = stats[2*C + CM + col];
      float mean = t1*(1.f/M);
      float var  = t2*(1.f/M) - mean*mean;
      float sc = bn1_g[col]*rsqrtf(var + EPSB);
      float sh = bn1_b[col] - mean*sc;
      hl[e] = h[(size_t)(row0+rl)*CM + col]*sc + sh;
    }
    __syncthreads();
    #pragma unroll
    for (int j = 0; j < 2; ++j){
      int e = tid + j*256;
      int c  = e & (C-1);
      int rl = e >> 5;
      float acc = b2[c];
      #pragma unroll
      for (int jj = 0; jj < CM; ++jj) acc += hl[rl*CM + jj] * w2l[jj*C + c];
      int row = row0 + rl;
      out[(size_t)row*C + c] = y[(size_t)row*C + c] + acc;
    }
  }
}

// ---------------------------------------------------------------------------
extern "C" void kernel_launch(void* const* d_in, const int* in_sizes, int n_in,
                              void* d_out, int out_size, void* d_ws, size_t ws_size,
                              hipStream_t stream) {
  const float* positions = (const float*)d_in[0];
  const float* weights   = (const float*)d_in[1];
  const float* kpos      = (const float*)d_in[2];
  const float* conv_w    = (const float*)d_in[3];
  const float* bn_g      = (const float*)d_in[4];
  const float* bn_b      = (const float*)d_in[5];
  const float* w1        = (const float*)d_in[6];
  const float* b1        = (const float*)d_in[7];
  const float* bn1_g     = (const float*)d_in[8];
  const float* bn1_b     = (const float*)d_in[9];
  const float* w2        = (const float*)d_in[10];
  const float* b2        = (const float*)d_in[11];
  float* out = (float*)d_out;

  float* ws = (float*)d_ws;
  size_t off = 0;
  _Float16* cwh = (_Float16*)(ws + off); off += (size_t)128*CHUNK_F16/2;
  float* part  = ws + off; off += (size_t)SCH*M*C;
  float* z     = ws + off; off += (size_t)M*C;
  float* y     = ws + off; off += (size_t)M*C;
  float* h     = ws + off; off += (size_t)M*CM;
  float* stats = ws + off; off += 320;
  int* bar     = (int*)(ws + off); off += 4;

  hipMemsetAsync(bar, 0, 4*sizeof(int), stream);
  fused_all<<<GRID_BLOCKS, 256, 0, stream>>>(
      positions, weights, kpos, conv_w, bn_g, bn_b, w1, b1,
      bn1_g, bn1_b, w2, b2, out, cwh, part, z, y, h, stats, bar);
}

// Round 5
// 266.022 us; speedup vs baseline: 1.0515x; 1.0515x over previous
//
#include <hip/hip_runtime.h>

#define BB 4
#define NN 1024
#define KK 9
#define C  32
#define CM 128
#define M  (BB*NN)       // 4096 rows
#define EPSB 1e-5f
#define SLOPE 0.01f

#define GRID_BLOCKS 512
#define SCH 4            // n-chunks (part slots)
#define NCH 256          // n per chunk
#define KPAD 296         // padded row stride (f16) for comp_w tiles
#define CHUNK_F16 (32*KPAD)   // 9472 f16 per (b,nc,sub) tile

// barrier memory layout (ints): cnt[phase] at p*16 (64B apart);
// flags start at offset 64, flag(p,b) at 64 + (p*512+b)*4 (16B stride)
#define BAR_INTS (64 + 4*GRID_BLOCKS*4)

typedef _Float16 f16x8 __attribute__((ext_vector_type(8)));
typedef _Float16 f16x4 __attribute__((ext_vector_type(4)));
typedef float    f32x4 __attribute__((ext_vector_type(4)));

__device__ __forceinline__ float leaky(float x){ return x > 0.f ? x : SLOPE*x; }

// Broadcast grid barrier: 512 spinners on one line melted the coherence
// point (r4: ~45us/barrier). Here only block 0 spins on the arrival counter;
// it then release-stores one flag PER BLOCK (16B stride -> spread lines),
// and every other block spins on its own flag. Release/acquire at agent
// scope gives cross-XCD visibility transitively.
__device__ __forceinline__ void gridbar(int* barmem, int phase, bool spin){
  __syncthreads();
  if (threadIdx.x == 0){
    __hip_atomic_fetch_add(&barmem[phase*16], 1, __ATOMIC_RELEASE,
                           __HIP_MEMORY_SCOPE_AGENT);
  }
  if (blockIdx.x == 0){
    if (threadIdx.x == 0){
      while (__hip_atomic_load(&barmem[phase*16], __ATOMIC_ACQUIRE,
                               __HIP_MEMORY_SCOPE_AGENT) < GRID_BLOCKS){
        __builtin_amdgcn_s_sleep(8);
      }
    }
    __syncthreads();
    for (int b = threadIdx.x; b < GRID_BLOCKS; b += 256){
      __hip_atomic_store(&barmem[64 + (phase*GRID_BLOCKS + b)*4], 1,
                         __ATOMIC_RELEASE, __HIP_MEMORY_SCOPE_AGENT);
    }
    __syncthreads();
  } else if (spin){
    if (threadIdx.x == 0){
      while (__hip_atomic_load(&barmem[64 + (phase*GRID_BLOCKS + blockIdx.x)*4],
                               __ATOMIC_ACQUIRE, __HIP_MEMORY_SCOPE_AGENT) == 0){
        __builtin_amdgcn_s_sleep(8);
      }
    }
    __syncthreads();
  }
}

// ---------------------------------------------------------------------------
// One fused kernel, plain launch, 512 blocks x 256 threads, 5 phases.
// Phase bodies identical to the r2/r4-verified versions. 40KB LDS union,
// __launch_bounds__(256,2) -> 2 blocks/CU -> all 512 blocks co-resident.
// ---------------------------------------------------------------------------
__global__ __launch_bounds__(256, 2) void fused_all(
    const float* __restrict__ pos,
    const float* __restrict__ weights,
    const float* __restrict__ kpos,
    const float* __restrict__ conv_w,
    const float* __restrict__ bn_g,  const float* __restrict__ bn_b,
    const float* __restrict__ w1,    const float* __restrict__ b1,
    const float* __restrict__ bn1_g, const float* __restrict__ bn1_b,
    const float* __restrict__ w2,    const float* __restrict__ b2,
    float* __restrict__ out,
    _Float16* __restrict__ cwh,
    float* __restrict__ part,
    float* __restrict__ z,
    float* __restrict__ y,
    float* __restrict__ h,
    float* __restrict__ stats,
    int* __restrict__ bar)
{
  __shared__ __align__(16) char smem[40960];
  int bid = blockIdx.x;
  int tid = threadIdx.x;

  // ======== Phase A: comp_w f16 producer (+ zero stats) — 384 blocks ========
  if (bid == 0){ for (int i = tid; i < 320; i += 256) stats[i] = 0.f; }
  if (bid < 384){
    float* cwl = (float*)smem;     // 12 KB conv_w k-slice
    int kt  = bid % 3;
    int sub = (bid/3)&7, nc = (bid/24)&3, b = bid/96;

    const float4* cs = (const float4*)(conv_w + kt*3*C*C);
    float4* cd = (float4*)cwl;
    for (int v = tid; v < 768; v += 256) cd[v] = cs[v];

    int nl = tid & 31, dq = tid >> 5;
    int row = ((b*4 + nc)*8 + sub)*32 + nl;
    float wreg[32];
    const float4* wr = (const float4*)(weights + (size_t)row*C);
    #pragma unroll
    for (int j = 0; j < 8; ++j){
      float4 t = wr[j];
      wreg[4*j]=t.x; wreg[4*j+1]=t.y; wreg[4*j+2]=t.z; wreg[4*j+3]=t.w;
    }
    __syncthreads();

    _Float16* outb = cwh + (size_t)((b*4+nc)*8 + sub)*CHUNK_F16;
    const float4* cv = (const float4*)cwl;
    #pragma unroll
    for (int kl = 0; kl < 3; ++kl){
      float a0=0.f, a1=0.f, a2=0.f, a3=0.f;
      #pragma unroll
      for (int c = 0; c < C; ++c){
        float4 t = cv[kl*256 + c*8 + dq];
        a0 += wreg[c]*t.x; a1 += wreg[c]*t.y; a2 += wreg[c]*t.z; a3 += wreg[c]*t.w;
      }
      int k = kt*3 + kl;
      outb[(dq*4+0)*KPAD + k*32 + nl] = (_Float16)a0;
      outb[(dq*4+1)*KPAD + k*32 + nl] = (_Float16)a1;
      outb[(dq*4+2)*KPAD + k*32 + nl] = (_Float16)a2;
      outb[(dq*4+3)*KPAD + k*32 + nl] = (_Float16)a3;
    }
  }
  gridbar(bar, 0, true);

  // ======== Phase B: flash-style MFMA Gaussian mixture — all 512 blocks ====
  {
    _Float16* km = (_Float16*)smem;            // [i][K] 18944 B
    _Float16* cw = (_Float16*)(smem + 18944);  // [c][K] 18944 B
    float* pnl   = (float*)(smem + 37888);     // 2 KB
    int nc = bid & 3, it = (bid>>2)&31, b = bid>>7;
    int lane = tid & 63, wid = tid >> 6;
    int i0 = (wid>>1)*16, c0 = (wid&1)*16;
    int mm = lane & 15, quad = lane >> 4;

    const float* pbase = pos + (size_t)(b*NN + nc*NCH)*2;
    for (int v = tid; v < NCH*2; v += 256) pnl[v] = pbase[v];

    int ig = tid >> 3, np = tid & 7;
    float pix = pos[(size_t)(b*NN + it*32 + ig)*2];
    float piy = pos[(size_t)(b*NN + it*32 + ig)*2 + 1];
    float kx[KK], ky[KK];
    #pragma unroll
    for (int k = 0; k < KK; ++k){ kx[k] = kpos[2*k]; ky[k] = kpos[2*k+1]; }

    f32x4 acc = {0.f,0.f,0.f,0.f};
    __syncthreads();

    for (int s = 0; s < 8; ++s){
      const float4* srcs = (const float4*)(cwh + (size_t)((b*4+nc)*8 + s)*CHUNK_F16);
      float4* dst = (float4*)cw;
      for (int v = tid; v < CHUNK_F16/8; v += 256) dst[v] = srcs[v];

      float dx[4], dy[4];
      #pragma unroll
      for (int jj = 0; jj < 4; ++jj){
        int nl = np*4 + jj;
        dx[jj] = pix - pnl[2*(s*32+nl)];
        dy[jj] = piy - pnl[2*(s*32+nl)+1];
      }
      #pragma unroll
      for (int k = 0; k < KK; ++k){
        f16x4 ev;
        #pragma unroll
        for (int jj = 0; jj < 4; ++jj){
          float ddx = dx[jj]-kx[k], ddy = dy[jj]-ky[k];
          ev[jj] = (_Float16)__expf(-0.5f*(ddx*ddx + ddy*ddy));
        }
        *(f16x4*)&km[ig*KPAD + k*32 + np*4] = ev;
      }
      __syncthreads();

      #pragma unroll
      for (int ks = 0; ks < 9; ++ks){
        f16x8 a  = *(const f16x8*)&km[(i0+mm)*KPAD + ks*32 + quad*8];
        f16x8 bf = *(const f16x8*)&cw[(c0+mm)*KPAD + ks*32 + quad*8];
        acc = __builtin_amdgcn_mfma_f32_16x16x32_f16(a, bf, acc, 0, 0, 0);
      }
      __syncthreads();
    }

    int grow0 = b*NN + it*32 + i0;
    #pragma unroll
    for (int r = 0; r < 4; ++r){
      int grow = grow0 + quad*4 + r;
      part[((size_t)nc*M + grow)*C + c0 + mm] = acc[r];
    }
  }
  gridbar(bar, 1, true);

  // ======== Phase C: z = leaky(sum part) + channel stats — all blocks ======
  {
    float* ls1 = (float*)smem;
    float* ls2 = ls1 + C;
    if (tid < C){ ls1[tid]=0.f; ls2[tid]=0.f; }
    __syncthreads();
    size_t idx = (size_t)bid*256 + tid;
    float s = 0.f;
    #pragma unroll
    for (int p = 0; p < SCH; ++p) s += part[(size_t)p*M*C + idx];
    s = leaky(s);
    z[idx] = s;
    atomicAdd(&ls1[tid & (C-1)], s);
    atomicAdd(&ls2[tid & (C-1)], s*s);
    __syncthreads();
    if (tid < C){ atomicAdd(&stats[tid], ls1[tid]); atomicAdd(&stats[C+tid], ls2[tid]); }
  }
  gridbar(bar, 2, true);

  // ======== Phase D: BN + residual + MLP layer 1 + stats — 256 blocks ======
  if (bid < 256){
    float* w1l = (float*)smem;              // 16 KB
    float* yl  = (float*)(smem + 16384);    // 2 KB
    float* lt1 = (float*)(smem + 18432);    // 512 B
    float* lt2 = (float*)(smem + 18944);    // 512 B
    int row0 = bid * 16;
    for (int i = tid; i < C*CM; i += 256) w1l[i] = w1[i];
    if (tid < CM){ lt1[tid]=0.f; lt2[tid]=0.f; }
    #pragma unroll
    for (int j = 0; j < 2; ++j){
      int e = tid + j*256;
      int c  = e & (C-1);
      int rl = e >> 5;
      float s1 = stats[c], s2 = stats[C + c];
      float mean = s1 * (1.f/M);
      float var  = s2 * (1.f/M) - mean*mean;
      float sc = bn_g[c] * rsqrtf(var + EPSB);
      float sh = bn_b[c] - mean*sc;
      int row = row0 + rl;
      float v = z[(size_t)row*C + c]*sc + sh + weights[(size_t)row*C + c];
      yl[e] = v;
      y[(size_t)row*C + c] = v;
    }
    __syncthreads();
    #pragma unroll
    for (int j = 0; j < 8; ++j){
      int e = tid + j*256;
      int col = e & (CM-1);
      int rl  = e >> 7;
      float acc = b1[col];
      #pragma unroll
      for (int c = 0; c < C; ++c) acc += yl[rl*C + c] * w1l[c*CM + col];
      acc = leaky(acc);
      h[(size_t)(row0+rl)*CM + col] = acc;
      atomicAdd(&lt1[col], acc);
      atomicAdd(&lt2[col], acc*acc);
    }
    __syncthreads();
    if (tid < CM){
      atomicAdd(&stats[2*C + tid],      lt1[tid]);
      atomicAdd(&stats[2*C + CM + tid], lt2[tid]);
    }
  }
  // blocks >=256 just arrive (they don't run phase E)
  gridbar(bar, 3, bid < 256);
  if (bid >= 256) return;

  // ======== Phase E: BN1 + MLP layer 2 + final residual — 256 blocks =======
  {
    float* w2l = (float*)smem;              // 16 KB
    float* hl  = (float*)(smem + 16384);    // 8 KB
    int row0 = bid * 16;
    for (int i = tid; i < CM*C; i += 256) w2l[i] = w2[i];
    #pragma unroll
    for (int j = 0; j < 8; ++j){
      int e = tid + j*256;
      int col = e & (CM-1);
      int rl  = e >> 7;
      float t1 = stats[2*C + col], t2 = stats[2*C + CM + col];
      float mean = t1*(1.f/M);
      float var  = t2*(1.f/M) - mean*mean;
      float sc = bn1_g[col]*rsqrtf(var + EPSB);
      float sh = bn1_b[col] - mean*sc;
      hl[e] = h[(size_t)(row0+rl)*CM + col]*sc + sh;
    }
    __syncthreads();
    #pragma unroll
    for (int j = 0; j < 2; ++j){
      int e = tid + j*256;
      int c  = e & (C-1);
      int rl = e >> 5;
      float acc = b2[c];
      #pragma unroll
      for (int jj = 0; jj < CM; ++jj) acc += hl[rl*CM + jj] * w2l[jj*C + c];
      int row = row0 + rl;
      out[(size_t)row*C + c] = y[(size_t)row*C + c] + acc;
    }
  }
}

// ---------------------------------------------------------------------------
extern "C" void kernel_launch(void* const* d_in, const int* in_sizes, int n_in,
                              void* d_out, int out_size, void* d_ws, size_t ws_size,
                              hipStream_t stream) {
  const float* positions = (const float*)d_in[0];
  const float* weights   = (const float*)d_in[1];
  const float* kpos      = (const float*)d_in[2];
  const float* conv_w    = (const float*)d_in[3];
  const float* bn_g      = (const float*)d_in[4];
  const float* bn_b      = (const float*)d_in[5];
  const float* w1        = (const float*)d_in[6];
  const float* b1        = (const float*)d_in[7];
  const float* bn1_g     = (const float*)d_in[8];
  const float* bn1_b     = (const float*)d_in[9];
  const float* w2        = (const float*)d_in[10];
  const float* b2        = (const float*)d_in[11];
  float* out = (float*)d_out;

  float* ws = (float*)d_ws;
  size_t off = 0;
  _Float16* cwh = (_Float16*)(ws + off); off += (size_t)128*CHUNK_F16/2;
  float* part  = ws + off; off += (size_t)SCH*M*C;
  float* z     = ws + off; off += (size_t)M*C;
  float* y     = ws + off; off += (size_t)M*C;
  float* h     = ws + off; off += (size_t)M*CM;
  float* stats = ws + off; off += 320;
  int* bar     = (int*)(ws + off); off += BAR_INTS;

  hipMemsetAsync(bar, 0, BAR_INTS*sizeof(int), stream);
  fused_all<<<GRID_BLOCKS, 256, 0, stream>>>(
      positions, weights, kpos, conv_w, bn_g, bn_b, w1, b1,
      bn1_g, bn1_b, w2, b2, out, cwh, part, z, y, h, stats, bar);
}